// Round 6
// baseline (1211.257 us; speedup 1.0000x reference)
//
#include <hip/hip_runtime.h>
#include <math.h>

// Problem constants (shapes follow the reference; N and E derived from in_sizes)
#define DIMX   256
#define HEADS  16
#define QKD    8
#define DH     128           // HEADS*QKD
#define QKVW   512           // 2*DH + DIMX
#define INRPE  18
#define SCALE  0.35355339059327373f   // 8^-0.5

#define PIN(x) asm volatile("" : "+v"(x))

// ---------------------------------------------------------------------------
// Kernel 1: qkv = x @ Wqkv + b ; q-part pre-scaled by SCALE.
// Row layout (512 floats): [q*SCALE (128) | k (128) | v (256)]
// 128x128 tile, 256 threads, 8x8 microtile. Double-buffered LDS: next K-tile's
// global loads issue before compute on the current buffer; ONE barrier/iter.
// ---------------------------------------------------------------------------
__global__ __launch_bounds__(256) void qkv_gemm(
    const float* __restrict__ x, const float* __restrict__ W,
    const float* __restrict__ bias, float* __restrict__ qkv, int Nn)
{
    __shared__ float As[2][16][132];   // A^T tile: As[buf][k][row]
    __shared__ float Bs[2][16][132];   // B tile:  Bs[buf][k][col]

    int tid  = threadIdx.x;
    int row0 = blockIdx.x * 128;
    int col0 = blockIdx.y * 128;
    int tx = tid & 15, ty = tid >> 4;

    // staging addresses (fixed per thread)
    int aidx0 = tid, aidx1 = tid + 256;
    int arow0 = aidx0 >> 2, acol0 = (aidx0 & 3) * 4;
    int arow1 = aidx1 >> 2, acol1 = (aidx1 & 3) * 4;
    int brow0 = aidx0 >> 5, bcol0 = (aidx0 & 31) * 4;
    int brow1 = aidx1 >> 5, bcol1 = (aidx1 & 31) * 4;

    float acc[8][8] = {};
    float4 av0, av1, bv0, bv1;

    // ---- global load of tile k0 into regs
    #define LOADG(k0)  do {                                                        \
        av0 = make_float4(0.f,0.f,0.f,0.f); av1 = make_float4(0.f,0.f,0.f,0.f);    \
        if (row0 + arow0 < Nn) av0 = *(const float4*)&x[(size_t)(row0+arow0)*DIMX + (k0)+acol0]; \
        if (row0 + arow1 < Nn) av1 = *(const float4*)&x[(size_t)(row0+arow1)*DIMX + (k0)+acol1]; \
        bv0 = *(const float4*)&W[(size_t)((k0)+brow0)*QKVW + col0 + bcol0];        \
        bv1 = *(const float4*)&W[(size_t)((k0)+brow1)*QKVW + col0 + bcol1];        \
    } while (0)

    #define STORE_LDS(b) do {                                                      \
        As[b][acol0+0][arow0]=av0.x; As[b][acol0+1][arow0]=av0.y;                  \
        As[b][acol0+2][arow0]=av0.z; As[b][acol0+3][arow0]=av0.w;                  \
        As[b][acol1+0][arow1]=av1.x; As[b][acol1+1][arow1]=av1.y;                  \
        As[b][acol1+2][arow1]=av1.z; As[b][acol1+3][arow1]=av1.w;                  \
        *(float4*)&Bs[b][brow0][bcol0] = bv0;                                      \
        *(float4*)&Bs[b][brow1][bcol1] = bv1;                                      \
    } while (0)

    #define COMPUTE(b) do {                                                        \
        _Pragma("unroll")                                                          \
        for (int kk = 0; kk < 16; kk++) {                                          \
            float a0[8], b0[8];                                                    \
            *(float4*)&a0[0] = *(const float4*)&As[b][kk][ty * 8];                 \
            *(float4*)&a0[4] = *(const float4*)&As[b][kk][ty * 8 + 4];             \
            *(float4*)&b0[0] = *(const float4*)&Bs[b][kk][tx * 4];                 \
            *(float4*)&b0[4] = *(const float4*)&Bs[b][kk][64 + tx * 4];            \
            _Pragma("unroll")                                                      \
            for (int i = 0; i < 8; i++)                                            \
                _Pragma("unroll")                                                  \
                for (int j = 0; j < 8; j++)                                        \
                    acc[i][j] = fmaf(a0[i], b0[j], acc[i][j]);                     \
        }                                                                          \
    } while (0)

    LOADG(0);
    STORE_LDS(0);
    __syncthreads();
    int cur = 0;
    for (int k0 = 16; k0 < DIMX; k0 += 16) {
        LOADG(k0);            // in flight during compute below
        COMPUTE(cur);
        STORE_LDS(cur ^ 1);   // waits on the global loads here
        __syncthreads();
        cur ^= 1;
    }
    COMPUTE(cur);

    #undef LOADG
    #undef STORE_LDS
    #undef COMPUTE

    float sc = (blockIdx.y == 0) ? SCALE : 1.0f;   // col block 0 is entirely q
    float4 bb0 = *(const float4*)&bias[col0 + tx * 4];
    float4 bb1 = *(const float4*)&bias[col0 + 64 + tx * 4];
    #pragma unroll
    for (int i = 0; i < 8; i++) {
        int grow = row0 + ty * 8 + i;
        if (grow < Nn) {
            float4 o0, o1;
            o0.x = (acc[i][0] + bb0.x) * sc;
            o0.y = (acc[i][1] + bb0.y) * sc;
            o0.z = (acc[i][2] + bb0.z) * sc;
            o0.w = (acc[i][3] + bb0.w) * sc;
            o1.x = (acc[i][4] + bb1.x) * sc;
            o1.y = (acc[i][5] + bb1.y) * sc;
            o1.z = (acc[i][6] + bb1.z) * sc;
            o1.w = (acc[i][7] + bb1.w) * sc;
            *(float4*)&qkv[(size_t)grow * QKVW + col0 + tx * 4] = o0;
            *(float4*)&qkv[(size_t)grow * QKVW + col0 + 64 + tx * 4] = o1;
        }
    }
}

// ---------------------------------------------------------------------------
// CSR build: count -> scan -> scatter (grouped by source node s)
// ---------------------------------------------------------------------------
__global__ void count_kernel(const int* __restrict__ ei, int* __restrict__ deg, int E)
{
    int e = blockIdx.x * blockDim.x + threadIdx.x;
    if (e < E) atomicAdd(&deg[ei[e]], 1);
}

__global__ __launch_bounds__(1024) void scan_kernel(
    const int* __restrict__ deg, int* __restrict__ off, int n)
{
    __shared__ int part[1024];
    int tid = threadIdx.x;
    int chunk = (n + 1023) / 1024;
    int s = tid * chunk;
    int epos = min(s + chunk, n);
    int sum = 0;
    for (int i = s; i < epos; i++) sum += deg[i];
    part[tid] = sum;
    __syncthreads();
    for (int d = 1; d < 1024; d <<= 1) {
        int v = (tid >= d) ? part[tid - d] : 0;
        __syncthreads();
        part[tid] += v;
        __syncthreads();
    }
    int run = part[tid] - sum;   // exclusive base
    for (int i = s; i < epos; i++) { off[i] = run; run += deg[i]; }
    if (tid == 1023) off[n] = run;
}

__global__ void scatter_kernel(const int* __restrict__ ei,
                               const int* __restrict__ off, int* __restrict__ cur,
                               int2* __restrict__ elist, int E)
{
    int e = blockIdx.x * blockDim.x + threadIdx.x;
    if (e < E) {
        int s = ei[e];
        int t = ei[E + e];
        int pos = atomicAdd(&cur[s], 1);
        elist[off[s] + pos] = make_int2(e, t);
    }
}

// ---------------------------------------------------------------------------
// Kernel 2: fused node-centric attention, 2-slot software pipeline.
// One wave per node; lane l -> head l>>2, qk dims 2l,2l+1; v dims 4l..4l+3.
// Each iteration: COMPUTE slot (data loaded >=1 phase ago), then issue that
// slot's replacement loads -> gather latency overlaps the other slot's math.
// ---------------------------------------------------------------------------
__global__ __launch_bounds__(256, 3) void node_attn(
    const float* __restrict__ qkv, const int2* __restrict__ elist,
    const int* __restrict__ off, const float* __restrict__ edge_attr,
    const float* __restrict__ Wq_rpe, const float* __restrict__ bq_rpe,
    const float* __restrict__ Wk_rpe, const float* __restrict__ bk_rpe,
    float* __restrict__ out, int Nn)
{
    int wave = threadIdx.x >> 6;
    int lane = threadIdx.x & 63;
    int n = blockIdx.x * 4 + wave;
    if (n >= Nn) return;

    int c0 = lane * 2;

    // resident RPE weight columns for this lane's two qk dims
    float wq0[INRPE], wq1[INRPE], wk0[INRPE], wk1[INRPE];
    #pragma unroll
    for (int j = 0; j < INRPE; j++) {
        wq0[j] = Wq_rpe[j * DH + c0];
        wq1[j] = Wq_rpe[j * DH + c0 + 1];
        wk0[j] = Wk_rpe[j * DH + c0];
        wk1[j] = Wk_rpe[j * DH + c0 + 1];
        PIN(wq0[j]); PIN(wq1[j]); PIN(wk0[j]); PIN(wk1[j]);
    }
    float bq0 = bq_rpe[c0], bq1 = bq_rpe[c0 + 1];
    float bk0 = bk_rpe[c0], bk1 = bk_rpe[c0 + 1];

    float qs0 = qkv[(size_t)n * QKVW + c0];        // pre-scaled q
    float qs1 = qkv[(size_t)n * QKVW + c0 + 1];

    int beg = off[n], end = off[n + 1];

    float m = -INFINITY, lsum = 0.0f;
    float4 o = make_float4(0.f, 0.f, 0.f, 0.f);

    #define LOAD_EDGE(Ea, Ekt, Evt, ed) do {                                       \
        const float2* _p = (const float2*)(edge_attr + (size_t)(ed).x * INRPE);    \
        _Pragma("unroll")                                                          \
        for (int j = 0; j < 9; j++) Ea[j] = _p[j];                                 \
        Ekt = *(const float2*)&qkv[(size_t)(ed).y * QKVW + DH + c0];               \
        Evt = *(const float4*)&qkv[(size_t)(ed).y * QKVW + 2 * DH + 4 * lane];     \
    } while (0)

    #define COMPUTE_EDGE(Ea, Ekt, Evt) do {                                        \
        float _q0 = bq0, _q1 = bq1, _k0 = bk0, _k1 = bk1;                          \
        _Pragma("unroll")                                                          \
        for (int j = 0; j < 9; j++) {                                              \
            _q0 = fmaf(Ea[j].x, wq0[2*j], _q0); _q0 = fmaf(Ea[j].y, wq0[2*j+1], _q0); \
            _q1 = fmaf(Ea[j].x, wq1[2*j], _q1); _q1 = fmaf(Ea[j].y, wq1[2*j+1], _q1); \
            _k0 = fmaf(Ea[j].x, wk0[2*j], _k0); _k0 = fmaf(Ea[j].y, wk0[2*j+1], _k0); \
            _k1 = fmaf(Ea[j].x, wk1[2*j], _k1); _k1 = fmaf(Ea[j].y, wk1[2*j+1], _k1); \
        }                                                                          \
        float _cv = (qs0 + _q0) * (Ekt.x + _k0) + (qs1 + _q1) * (Ekt.y + _k1);     \
        _cv += __shfl_xor(_cv, 1, 64);                                             \
        _cv += __shfl_xor(_cv, 2, 64);                                             \
        float _mn = fmaxf(m, _cv);                                                 \
        float _al = __expf(m - _mn);                                               \
        float _ex = __expf(_cv - _mn);                                             \
        lsum = lsum * _al + _ex;                                                   \
        o.x = fmaf(_ex, Evt.x, o.x * _al);                                         \
        o.y = fmaf(_ex, Evt.y, o.y * _al);                                         \
        o.z = fmaf(_ex, Evt.z, o.z * _al);                                         \
        o.w = fmaf(_ex, Evt.w, o.w * _al);                                         \
        m = _mn;                                                                   \
    } while (0)

    float2 Pa[9], Qa[9];
    float2 Pkt, Qkt;
    float4 Pvt, Qvt;

    int i = beg;
    if (i < end)     { int2 e0 = elist[i];     LOAD_EDGE(Pa, Pkt, Pvt, e0); }
    if (i + 1 < end) { int2 e1 = elist[i + 1]; LOAD_EDGE(Qa, Qkt, Qvt, e1); }

    for (; i + 3 < end; i += 2) {
        int2 n0 = elist[i + 2];
        int2 n1 = elist[i + 3];
        COMPUTE_EDGE(Pa, Pkt, Pvt);        // consumes P (loaded last iter)
        LOAD_EDGE(Pa, Pkt, Pvt, n0);       // P's refill overlaps Q's compute
        COMPUTE_EDGE(Qa, Qkt, Qvt);
        LOAD_EDGE(Qa, Qkt, Qvt, n1);       // Q's refill overlaps next P compute
    }
    {
        int cnt = end - i;                  // 0..3 edges remain; P,Q hold i,i+1
        if (cnt >= 1) COMPUTE_EDGE(Pa, Pkt, Pvt);
        if (cnt >= 2) COMPUTE_EDGE(Qa, Qkt, Qvt);
        if (cnt >= 3) {
            int2 e2 = elist[i + 2];
            LOAD_EDGE(Pa, Pkt, Pvt, e2);
            COMPUTE_EDGE(Pa, Pkt, Pvt);
        }
    }
    #undef LOAD_EDGE
    #undef COMPUTE_EDGE

    float inv = 1.0f / (lsum + 1e-16f);   // deg=0 -> o=0 -> writes 0
    float4 r = make_float4(o.x * inv, o.y * inv, o.z * inv, o.w * inv);
    *(float4*)&out[(size_t)n * DIMX + 4 * lane] = r;
}

// ---------------------------------------------------------------------------
extern "C" void kernel_launch(void* const* d_in, const int* in_sizes, int n_in,
                              void* d_out, int out_size, void* d_ws, size_t ws_size,
                              hipStream_t stream)
{
    const float* x    = (const float*)d_in[0];
    const int*   ei   = (const int*)d_in[1];     // int32 (harness converts int64 -> int)
    const float* ea   = (const float*)d_in[2];
    const float* Wqkv = (const float*)d_in[3];
    const float* bqkv = (const float*)d_in[4];
    const float* Wk   = (const float*)d_in[5];
    const float* bk   = (const float*)d_in[6];
    const float* Wq   = (const float*)d_in[7];
    const float* bq   = (const float*)d_in[8];

    int Nn = in_sizes[0] / DIMX;
    int E  = in_sizes[1] / 2;
    float* out = (float*)d_out;

    // workspace layout
    float* qkv   = (float*)d_ws;                          // Nn*512 floats (102.4 MB)
    int*   deg   = (int*)d_ws + (size_t)Nn * QKVW;        // Nn
    int*   cur   = deg + Nn;                              // Nn
    int*   off   = cur + Nn;                              // Nn+1
    int2*  elist = (int2*)(off + ((Nn + 2) & ~1));        // E int2 (6.4 MB)

    hipMemsetAsync(deg, 0, sizeof(int) * 2 * (size_t)Nn, stream);  // deg + cur

    qkv_gemm<<<dim3((Nn + 127) / 128, QKVW / 128), 256, 0, stream>>>(x, Wqkv, bqkv, qkv, Nn);
    count_kernel<<<(E + 255) / 256, 256, 0, stream>>>(ei, deg, E);
    scan_kernel<<<1, 1024, 0, stream>>>(deg, off, Nn);
    scatter_kernel<<<(E + 255) / 256, 256, 0, stream>>>(ei, off, cur, elist, E);
    node_attn<<<(Nn + 3) / 4, 256, 0, stream>>>(qkv, elist, off, ea, Wq, bq, Wk, bk, out, Nn);
}

// Round 7
// 1089.674 us; speedup vs baseline: 1.1116x; 1.1116x over previous
//
#include <hip/hip_runtime.h>
#include <math.h>

// Problem constants (shapes follow the reference; N and E derived from in_sizes)
#define DIMX   256
#define HEADS  16
#define QKD    8
#define DH     128           // HEADS*QKD
#define QKVW   512           // 2*DH + DIMX
#define INRPE  18
#define SCALE  0.35355339059327373f   // 8^-0.5

typedef short bf16x8 __attribute__((ext_vector_type(8)));
typedef float f32x4  __attribute__((ext_vector_type(4)));

__device__ __forceinline__ unsigned short f2bf(float f) {
    unsigned u = __float_as_uint(f);
    u = u + 0x7FFF + ((u >> 16) & 1);     // round-to-nearest-even
    return (unsigned short)(u >> 16);
}

// ---------------------------------------------------------------------------
// Convert x (Nn x 256 fp32) -> bf16, 8 elems/thread
// ---------------------------------------------------------------------------
__global__ __launch_bounds__(256) void conv_x(
    const float* __restrict__ x, unsigned short* __restrict__ xb, long n8)
{
    long i = (long)blockIdx.x * blockDim.x + threadIdx.x;
    if (i >= n8) return;
    float4 a = *(const float4*)&x[i * 8];
    float4 b = *(const float4*)&x[i * 8 + 4];
    bf16x8 p;
    p[0] = (short)f2bf(a.x); p[1] = (short)f2bf(a.y);
    p[2] = (short)f2bf(a.z); p[3] = (short)f2bf(a.w);
    p[4] = (short)f2bf(b.x); p[5] = (short)f2bf(b.y);
    p[6] = (short)f2bf(b.z); p[7] = (short)f2bf(b.w);
    *(bf16x8*)(xb + i * 8) = p;
}

// Convert + transpose Wqkv (256x512 fp32) -> Wt (512x256 bf16), Wt[n][k]=W[k][n]
__global__ __launch_bounds__(256) void conv_wt(
    const float* __restrict__ W, unsigned short* __restrict__ Wt)
{
    int i = blockIdx.x * blockDim.x + threadIdx.x;   // i = n*256 + k; grid exact
    int n = i >> 8, k = i & 255;
    Wt[i] = f2bf(W[k * QKVW + n]);
}

// ---------------------------------------------------------------------------
// Kernel 1: qkv = x @ Wqkv + b via bf16 MFMA (fp32 accum), q-part pre-scaled.
// LDS-free: per wave, 64x64 tile = 4x4 frags of 16x16x32 MFMA; A/B frags are
// 16B contiguous global loads (x row-major bf16; W pre-transposed to [n][k]).
// A-frag: A[m=lane&15][k=quad*8+j]; B-frag: B[k=quad*8+j][n=lane&15];
// C/D: row=quad*4+reg, col=lane&15 (m89-verified layouts).
// ---------------------------------------------------------------------------
__global__ __launch_bounds__(256) void qkv_gemm_mfma(
    const unsigned short* __restrict__ xb, const unsigned short* __restrict__ Wt,
    const float* __restrict__ bias, float* __restrict__ qkv, int Nn)
{
    int lane = threadIdx.x & 63, wid = threadIdx.x >> 6;
    int row0 = blockIdx.x * 128 + (wid >> 1) * 64;
    int col0 = blockIdx.y * 128 + (wid & 1) * 64;
    int rsel = lane & 15, quad = lane >> 4;

    f32x4 zero = {0.f, 0.f, 0.f, 0.f};
    f32x4 acc[4][4];
    #pragma unroll
    for (int mi = 0; mi < 4; mi++)
        #pragma unroll
        for (int ni = 0; ni < 4; ni++) acc[mi][ni] = zero;

    // clamped A row indices (rows >= Nn read row Nn-1; never stored)
    int ridx[4];
    #pragma unroll
    for (int mi = 0; mi < 4; mi++) {
        int r = row0 + mi * 16 + rsel;
        ridx[mi] = (r < Nn) ? r : (Nn - 1);
    }

    #pragma unroll
    for (int k0 = 0; k0 < DIMX; k0 += 32) {
        bf16x8 a[4], b[4];
        #pragma unroll
        for (int mi = 0; mi < 4; mi++)
            a[mi] = *(const bf16x8*)(xb + (size_t)ridx[mi] * DIMX + k0 + quad * 8);
        #pragma unroll
        for (int ni = 0; ni < 4; ni++) {
            int c = col0 + ni * 16 + rsel;
            b[ni] = *(const bf16x8*)(Wt + (size_t)c * DIMX + k0 + quad * 8);
        }
        #pragma unroll
        for (int mi = 0; mi < 4; mi++)
            #pragma unroll
            for (int ni = 0; ni < 4; ni++)
                acc[mi][ni] = __builtin_amdgcn_mfma_f32_16x16x32_bf16(
                    a[mi], b[ni], acc[mi][ni], 0, 0, 0);
    }

    float sc = (blockIdx.y == 0) ? SCALE : 1.0f;   // col block 0 = entire q region
    float bv[4];
    #pragma unroll
    for (int ni = 0; ni < 4; ni++) bv[ni] = bias[col0 + ni * 16 + rsel];

    #pragma unroll
    for (int mi = 0; mi < 4; mi++) {
        #pragma unroll
        for (int reg = 0; reg < 4; reg++) {
            int gr = row0 + mi * 16 + quad * 4 + reg;
            if (gr < Nn) {
                #pragma unroll
                for (int ni = 0; ni < 4; ni++) {
                    int gc = col0 + ni * 16 + rsel;
                    qkv[(size_t)gr * QKVW + gc] = (acc[mi][ni][reg] + bv[ni]) * sc;
                }
            }
        }
    }
}

// ---------------------------------------------------------------------------
// CSR build: count -> scan -> scatter (grouped by source node s)
// ---------------------------------------------------------------------------
__global__ void count_kernel(const int* __restrict__ ei, int* __restrict__ deg, int E)
{
    int e = blockIdx.x * blockDim.x + threadIdx.x;
    if (e < E) atomicAdd(&deg[ei[e]], 1);
}

__global__ __launch_bounds__(1024) void scan_kernel(
    const int* __restrict__ deg, int* __restrict__ off, int n)
{
    __shared__ int part[1024];
    int tid = threadIdx.x;
    int chunk = (n + 1023) / 1024;
    int s = tid * chunk;
    int epos = min(s + chunk, n);
    int sum = 0;
    for (int i = s; i < epos; i++) sum += deg[i];
    part[tid] = sum;
    __syncthreads();
    for (int d = 1; d < 1024; d <<= 1) {
        int v = (tid >= d) ? part[tid - d] : 0;
        __syncthreads();
        part[tid] += v;
        __syncthreads();
    }
    int run = part[tid] - sum;   // exclusive base
    for (int i = s; i < epos; i++) { off[i] = run; run += deg[i]; }
    if (tid == 1023) off[n] = run;
}

__global__ void scatter_kernel(const int* __restrict__ ei,
                               const int* __restrict__ off, int* __restrict__ cur,
                               int2* __restrict__ elist, int E)
{
    int e = blockIdx.x * blockDim.x + threadIdx.x;
    if (e < E) {
        int s = ei[e];
        int t = ei[E + e];
        int pos = atomicAdd(&cur[s], 1);
        elist[off[s] + pos] = make_int2(e, t);
    }
}

// ---------------------------------------------------------------------------
// Kernel 2: fused node-centric attention. One wave per node (R2 loop shape —
// manual unroll/pipelining proven counterproductive in R4/R6).
// RPE weights live in LDS (19KB/block, shared by 4 waves) instead of 150
// regs/wave of AGPR: __launch_bounds__(256,5) caps regs ~102 so the compiler
// cannot hoist them back -> 5 waves/SIMD instead of 3 for latency hiding.
// ---------------------------------------------------------------------------
__global__ __launch_bounds__(256, 5) void node_attn(
    const float* __restrict__ qkv, const int2* __restrict__ elist,
    const int* __restrict__ off, const float* __restrict__ edge_attr,
    const float* __restrict__ Wq_rpe, const float* __restrict__ bq_rpe,
    const float* __restrict__ Wk_rpe, const float* __restrict__ bk_rpe,
    float* __restrict__ out, int Nn)
{
    __shared__ float sWq[INRPE * DH];
    __shared__ float sWk[INRPE * DH];
    for (int i = threadIdx.x; i < INRPE * DH; i += 256) {
        sWq[i] = Wq_rpe[i];
        sWk[i] = Wk_rpe[i];
    }
    __syncthreads();

    int wave = threadIdx.x >> 6;
    int lane = threadIdx.x & 63;
    int n = blockIdx.x * 4 + wave;
    if (n >= Nn) return;

    int c0 = lane * 2;

    float bq0 = bq_rpe[c0], bq1 = bq_rpe[c0 + 1];
    float bk0 = bk_rpe[c0], bk1 = bk_rpe[c0 + 1];
    float qs0 = qkv[(size_t)n * QKVW + c0];        // pre-scaled q
    float qs1 = qkv[(size_t)n * QKVW + c0 + 1];

    int beg = off[n], end = off[n + 1];

    float m = -INFINITY, lsum = 0.0f;
    float4 o = make_float4(0.f, 0.f, 0.f, 0.f);

    for (int i = beg; i < end; i++) {
        int2 et = elist[i];

        // gathers issue first; vmcnt waits land after the LDS/FMA work below
        float2 kt = *(const float2*)&qkv[(size_t)et.y * QKVW + DH + c0];
        float4 vt = *(const float4*)&qkv[(size_t)et.y * QKVW + 2 * DH + 4 * lane];
        const float2* ea2 = (const float2*)(edge_attr + (size_t)et.x * INRPE);

        float q0 = bq0, q1 = bq1, k0a = bk0, k1a = bk1;
        #pragma unroll
        for (int ja = 0; ja < 9; ja++) {
            float2 av  = ea2[ja];                                        // attr 2ja, 2ja+1
            float2 wqa = *(const float2*)&sWq[(2 * ja)     * DH + c0];   // b64, 2/bank: free
            float2 wqb = *(const float2*)&sWq[(2 * ja + 1) * DH + c0];
            float2 wka = *(const float2*)&sWk[(2 * ja)     * DH + c0];
            float2 wkb = *(const float2*)&sWk[(2 * ja + 1) * DH + c0];
            q0  = fmaf(av.x, wqa.x, q0);  q1  = fmaf(av.x, wqa.y, q1);
            q0  = fmaf(av.y, wqb.x, q0);  q1  = fmaf(av.y, wqb.y, q1);
            k0a = fmaf(av.x, wka.x, k0a); k1a = fmaf(av.x, wka.y, k1a);
            k0a = fmaf(av.y, wkb.x, k0a); k1a = fmaf(av.y, wkb.y, k1a);
        }

        float cv = (qs0 + q0) * (kt.x + k0a) + (qs1 + q1) * (kt.y + k1a);
        cv += __shfl_xor(cv, 1, 64);
        cv += __shfl_xor(cv, 2, 64);

        float mn = fmaxf(m, cv);
        float alpha = __expf(m - mn);     // first edge: exp(-inf)=0
        float ex = __expf(cv - mn);
        lsum = lsum * alpha + ex;
        o.x = fmaf(ex, vt.x, o.x * alpha);
        o.y = fmaf(ex, vt.y, o.y * alpha);
        o.z = fmaf(ex, vt.z, o.z * alpha);
        o.w = fmaf(ex, vt.w, o.w * alpha);
        m = mn;
    }

    float inv = 1.0f / (lsum + 1e-16f);   // deg=0 -> o=0 -> writes 0
    float4 r = make_float4(o.x * inv, o.y * inv, o.z * inv, o.w * inv);
    *(float4*)&out[(size_t)n * DIMX + 4 * lane] = r;
}

// ---------------------------------------------------------------------------
extern "C" void kernel_launch(void* const* d_in, const int* in_sizes, int n_in,
                              void* d_out, int out_size, void* d_ws, size_t ws_size,
                              hipStream_t stream)
{
    const float* x    = (const float*)d_in[0];
    const int*   ei   = (const int*)d_in[1];     // int32 (harness converts int64 -> int)
    const float* ea   = (const float*)d_in[2];
    const float* Wqkv = (const float*)d_in[3];
    const float* bqkv = (const float*)d_in[4];
    const float* Wk   = (const float*)d_in[5];
    const float* bk   = (const float*)d_in[6];
    const float* Wq   = (const float*)d_in[7];
    const float* bq   = (const float*)d_in[8];

    int Nn = in_sizes[0] / DIMX;
    int E  = in_sizes[1] / 2;
    float* out = (float*)d_out;

    // workspace layout
    float*          qkv = (float*)d_ws;                       // Nn*512 f32 (102.4 MB)
    unsigned short* xb  = (unsigned short*)(qkv + (size_t)Nn * QKVW);  // Nn*256 bf16 (25.6 MB)
    unsigned short* wt  = xb + (size_t)Nn * DIMX;             // 512*256 bf16 (256 KB)
    int*   deg   = (int*)(wt + QKVW * DIMX);                  // Nn
    int*   cur   = deg + Nn;                                  // Nn
    int*   off   = cur + Nn;                                  // Nn+1
    int2*  elist = (int2*)(off + ((Nn + 2) & ~1));            // E int2 (6.4 MB)

    hipMemsetAsync(deg, 0, sizeof(int) * 2 * (size_t)Nn, stream);  // deg + cur

    long n8 = (long)Nn * (DIMX / 8);
    conv_x<<<(int)((n8 + 255) / 256), 256, 0, stream>>>(x, xb, n8);
    conv_wt<<<(QKVW * DIMX) / 256, 256, 0, stream>>>(Wqkv, wt);

    qkv_gemm_mfma<<<dim3((Nn + 127) / 128, QKVW / 128), 256, 0, stream>>>(
        xb, wt, bqkv, qkv, Nn);

    count_kernel<<<(E + 255) / 256, 256, 0, stream>>>(ei, deg, E);
    scan_kernel<<<1, 1024, 0, stream>>>(deg, off, Nn);
    scatter_kernel<<<(E + 255) / 256, 256, 0, stream>>>(ei, off, cur, elist, E);

    node_attn<<<(Nn + 3) / 4, 256, 0, stream>>>(qkv, elist, off, ea, Wq, bq, Wk, bk, out, Nn);
}